// Round 4
// baseline (108.618 us; speedup 1.0000x reference)
//
#include <hip/hip_runtime.h>

// VectorQuantizer, round 4: E in registers (per-wave 128-code slice), X in LDS,
// barrier-free main loop, cross-wave argmin merge, fused last-block finalize.
// inputs: in [32,64,64,64] fp32 NCHW, emb [512,64] fp32.
// out[0:8388608] = quantized NCHW, out[8388608] = loss.
// ws: [0,65536)B emb bf16; [65536,+2048) npm = -0.5*(1+||e||^2); [67584,+4096) partials;
//     [71680] ticket counter.

#define D 64
#define K_EMB 512
#define HW 4096
#define CHW (D * HW)
#define OUT_ELEMS 8388608
#define NB_MAIN 1024 // 131072 rows / 128 rows per block
#define SWZ(r) ((((r) ^ ((r) >> 2))) & 7)

typedef __attribute__((ext_vector_type(8))) short short8;
typedef __attribute__((ext_vector_type(4))) float f32x4;

__device__ __forceinline__ unsigned short f2bf(float f) {
    unsigned u = __float_as_uint(f);
    u += 0x7FFFu + ((u >> 16) & 1u); // RNE
    return (unsigned short)(u >> 16);
}
__device__ __forceinline__ float bf2f(unsigned short h) {
    return __uint_as_float(((unsigned)h) << 16);
}
__device__ __forceinline__ unsigned umin32(unsigned a, unsigned b) { return a <= b ? a : b; }

// Prep: codebook fp32 -> bf16 rows, npm = -0.5*(1+||e||^2), zero the ticket.
__global__ void vq_prep(const float* __restrict__ emb, unsigned short* __restrict__ ebf,
                        float* __restrict__ npm, unsigned* __restrict__ cnt) {
    if (blockIdx.x == 0 && threadIdx.x == 0)
        __hip_atomic_store(cnt, 0u, __ATOMIC_RELAXED, __HIP_MEMORY_SCOPE_AGENT);
    int k = blockIdx.x * 256 + threadIdx.x; // <<<2,256>>>
    const float4* e4 = reinterpret_cast<const float4*>(emb + k * D);
    unsigned short h[D];
    float acc = 0.f;
#pragma unroll
    for (int i = 0; i < 16; ++i) {
        float4 v = e4[i];
        acc += v.x * v.x + v.y * v.y + v.z * v.z + v.w * v.w;
        h[4 * i + 0] = f2bf(v.x); h[4 * i + 1] = f2bf(v.y);
        h[4 * i + 2] = f2bf(v.z); h[4 * i + 3] = f2bf(v.w);
    }
    npm[k] = -0.5f * (1.0f + acc);
    uint4* dst = reinterpret_cast<uint4*>(ebf + k * D);
#pragma unroll
    for (int i = 0; i < 8; ++i) {
        uint4 p;
        p.x = (unsigned)h[8 * i + 0] | ((unsigned)h[8 * i + 1] << 16);
        p.y = (unsigned)h[8 * i + 2] | ((unsigned)h[8 * i + 3] << 16);
        p.z = (unsigned)h[8 * i + 4] | ((unsigned)h[8 * i + 5] << 16);
        p.w = (unsigned)h[8 * i + 6] | ((unsigned)h[8 * i + 7] << 16);
        dst[i] = p;
    }
}

__global__ __launch_bounds__(256, 2) void vq_mfma(const float* __restrict__ in,
                                                  const unsigned short* __restrict__ ebf,
                                                  const float* __restrict__ npm,
                                                  const float* __restrict__ emb,
                                                  float* __restrict__ out,
                                                  float* __restrict__ partials,
                                                  unsigned* __restrict__ cnt) {
    __shared__ __align__(16) char ldsX[16384]; // 128 rows x 128B bf16, swizzled
    __shared__ unsigned keysS[4][128];
    __shared__ int bestkS[128];
    __shared__ float red4[4];
    __shared__ float fin[256];
    __shared__ int doneF;

    const int tid = threadIdx.x;
    const int lane = tid & 63;
    const int w = tid >> 6;
    const int col = lane & 15;
    const int dg = lane >> 4;
    const int bid = blockIdx.x;
    const int n = bid >> 5;
    const int hw0 = (bid & 31) << 7;

    // ---- stage X tile: NCHW -> [row][d] bf16, swizzled ----
    {
        const int row = tid & 127;
        const int half = tid >> 7;
        const float* xb = in + n * CHW + hw0 + row;
#pragma unroll
        for (int cg = 0; cg < 4; ++cg) {
            const int cgi = half * 4 + cg;
            unsigned short h[8];
#pragma unroll
            for (int j = 0; j < 8; ++j) h[j] = f2bf(xb[(cgi * 8 + j) * HW]);
            uint4 p;
            p.x = (unsigned)h[0] | ((unsigned)h[1] << 16);
            p.y = (unsigned)h[2] | ((unsigned)h[3] << 16);
            p.z = (unsigned)h[4] | ((unsigned)h[5] << 16);
            p.w = (unsigned)h[6] | ((unsigned)h[7] << 16);
            *reinterpret_cast<uint4*>(ldsX + row * 128 + ((cgi ^ SWZ(row)) * 16)) = p;
        }
    }

    // ---- wave w's persistent E slice: codes w*128 + ct*16 + col, ct = 0..7 ----
    // Issued before the barrier so HBM/L2 latency hides under the X-stage drain.
    const int kbase = w * 128 + col;
    short8 ef[8][2];
    float npv[8];
    {
        const short8* e8 = reinterpret_cast<const short8*>(ebf);
#pragma unroll
        for (int ct = 0; ct < 8; ++ct) {
            const int k = kbase + ct * 16;
            ef[ct][0] = e8[k * 8 + dg];
            ef[ct][1] = e8[k * 8 + 4 + dg];
            npv[ct] = npm[k];
        }
    }
    __syncthreads();

    // ---- main loop: all 128 rows x this wave's 128 codes; regs + LDS only ----
    unsigned best[8][4];
#pragma unroll
    for (int rt = 0; rt < 8; ++rt)
#pragma unroll
        for (int i = 0; i < 4; ++i) best[rt][i] = 0xFFFFFFFFu;

#pragma unroll
    for (int rt = 0; rt < 8; ++rt) {
        const int row = rt * 16 + col;
        short8 a0 = *reinterpret_cast<const short8*>(
            ldsX + row * 128 + ((dg ^ SWZ(row)) * 16));
        short8 a1 = *reinterpret_cast<const short8*>(
            ldsX + row * 128 + (((4 + dg) ^ SWZ(row)) * 16));
#pragma unroll
        for (int ct = 0; ct < 8; ++ct) {
            // acc = x.e - 0.5*(1+||e||^2) = -crit/2 < 0; among negatives the
            // smallest uint is the least-negative float = smallest crit.
            f32x4 acc = {npv[ct], npv[ct], npv[ct], npv[ct]};
            acc = __builtin_amdgcn_mfma_f32_16x16x32_bf16(a0, ef[ct][0], acc, 0, 0, 0);
            acc = __builtin_amdgcn_mfma_f32_16x16x32_bf16(a1, ef[ct][1], acc, 0, 0, 0);
            const unsigned kc = (unsigned)(kbase + ct * 16);
#pragma unroll
            for (int i = 0; i < 4; ++i) {
                unsigned key = (__float_as_uint(acc[i]) & 0xFFFFFE00u) | kc;
                best[rt][i] = umin32(best[rt][i], key);
            }
        }
    }

    // ---- per-row argmin: reduce across the 16 code-columns, then across waves ----
#pragma unroll
    for (int rt = 0; rt < 8; ++rt)
#pragma unroll
        for (int i = 0; i < 4; ++i) {
            unsigned k = best[rt][i];
#pragma unroll
            for (int s = 1; s < 16; s <<= 1)
                k = umin32(k, (unsigned)__shfl_xor((int)k, s, 64));
            if (col == 0) keysS[w][rt * 16 + dg * 4 + i] = k;
        }
    __syncthreads();
    if (tid < 128) {
        unsigned k = umin32(umin32(keysS[0][tid], keysS[1][tid]),
                            umin32(keysS[2][tid], keysS[3][tid]));
        bestkS[tid] = (int)(k & 511u);
    }
    __syncthreads();

    // ---- epilogue: thread owns 4 rows x 8 channels ----
    const int rg = tid & 31;  // row group (4 rows)
    const int cs = tid >> 5;  // channel set (8 channels)
    int kk[4];
#pragma unroll
    for (int j = 0; j < 4; ++j) kk[j] = bestkS[rg * 4 + j];
    float ej[4][8];
#pragma unroll
    for (int j = 0; j < 4; ++j) {
        const float4* ep = reinterpret_cast<const float4*>(emb + kk[j] * D + cs * 8);
        *reinterpret_cast<float4*>(&ej[j][0]) = ep[0];
        *reinterpret_cast<float4*>(&ej[j][4]) = ep[1];
    }
    float lsum = 0.f;
#pragma unroll
    for (int j = 0; j < 4; ++j) {
        const int r = rg * 4 + j;
        short8 x8 = *reinterpret_cast<const short8*>(
            ldsX + r * 128 + ((cs ^ SWZ(r)) * 16));
#pragma unroll
        for (int t = 0; t < 8; ++t) {
            float d = ej[j][t] - bf2f((unsigned short)x8[t]);
            lsum = fmaf(d, d, lsum);
        }
    }
    float* obase = out + n * CHW + hw0 + rg * 4;
#pragma unroll
    for (int t = 0; t < 8; ++t) {
        float4 st;
        st.x = ej[0][t]; st.y = ej[1][t]; st.z = ej[2][t]; st.w = ej[3][t];
        *reinterpret_cast<float4*>(obase + (cs * 8 + t) * HW) = st;
    }

    // ---- loss partial + deterministic last-block finalize ----
#pragma unroll
    for (int s = 1; s < 64; s <<= 1) lsum += __shfl_xor(lsum, s, 64);
    if (lane == 0) red4[w] = lsum;
    __syncthreads();
    if (tid == 0) {
        float p = red4[0] + red4[1] + red4[2] + red4[3];
        __hip_atomic_store(&partials[bid], p, __ATOMIC_RELAXED, __HIP_MEMORY_SCOPE_AGENT);
        __threadfence(); // release: partials visible before ticket
        unsigned t = atomicAdd(cnt, 1u);
        doneF = (t == NB_MAIN - 1) ? 1 : 0;
    }
    __syncthreads();
    if (doneF) {
        __threadfence(); // acquire
        float a = 0.f;
#pragma unroll
        for (int i = 0; i < 4; ++i)
            a += __hip_atomic_load(&partials[tid + 256 * i], __ATOMIC_RELAXED,
                                   __HIP_MEMORY_SCOPE_AGENT);
        fin[tid] = a;
        __syncthreads();
        for (int t2 = 128; t2 > 0; t2 >>= 1) {
            if (tid < t2) fin[tid] += fin[tid + t2];
            __syncthreads();
        }
        if (tid == 0) out[OUT_ELEMS] = 1.25f * fin[0] * (1.0f / (float)OUT_ELEMS);
    }
}

extern "C" void kernel_launch(void* const* d_in, const int* in_sizes, int n_in,
                              void* d_out, int out_size, void* d_ws, size_t ws_size,
                              hipStream_t stream) {
    const float* in = (const float*)d_in[0];
    const float* emb = (const float*)d_in[1];
    float* out = (float*)d_out;
    unsigned short* ebf = (unsigned short*)d_ws;
    float* npm = (float*)((char*)d_ws + 65536);
    float* partials = (float*)((char*)d_ws + 67584);
    unsigned* cnt = (unsigned*)((char*)d_ws + 71680);

    vq_prep<<<2, 256, 0, stream>>>(emb, ebf, npm, cnt);
    vq_mfma<<<NB_MAIN, 256, 0, stream>>>(in, ebf, npm, emb, out, partials, cnt);
}

// Round 5
// 67.702 us; speedup vs baseline: 1.6044x; 1.6044x over previous
//
#include <hip/hip_runtime.h>

// VectorQuantizer, round 5: E in registers in 2 groups of 64 codes (32 VGPR
// reused), X in LDS, best[8][4] accumulated across groups, single reduce,
// barrier-light, fused last-block finalize.
// inputs: in [32,64,64,64] fp32 NCHW, emb [512,64] fp32.
// out[0:8388608] = quantized NCHW, out[8388608] = loss.
// ws: [0,65536)B emb bf16; [65536,+2048) npm = -0.5*(1+||e||^2); [67584,+4096) partials;
//     [71680] ticket counter.

#define D 64
#define K_EMB 512
#define HW 4096
#define CHW (D * HW)
#define OUT_ELEMS 8388608
#define NB_MAIN 1024 // 131072 rows / 128 rows per block
#define SWZ(r) ((((r) ^ ((r) >> 2))) & 7)

typedef __attribute__((ext_vector_type(8))) short short8;
typedef __attribute__((ext_vector_type(4))) float f32x4;

__device__ __forceinline__ unsigned short f2bf(float f) {
    unsigned u = __float_as_uint(f);
    u += 0x7FFFu + ((u >> 16) & 1u); // RNE
    return (unsigned short)(u >> 16);
}
__device__ __forceinline__ float bf2f(unsigned short h) {
    return __uint_as_float(((unsigned)h) << 16);
}
__device__ __forceinline__ unsigned umin32(unsigned a, unsigned b) { return a <= b ? a : b; }

// Prep: codebook fp32 -> bf16 rows, npm = -0.5*(1+||e||^2), zero the ticket.
__global__ void vq_prep(const float* __restrict__ emb, unsigned short* __restrict__ ebf,
                        float* __restrict__ npm, unsigned* __restrict__ cnt) {
    if (blockIdx.x == 0 && threadIdx.x == 0)
        __hip_atomic_store(cnt, 0u, __ATOMIC_RELAXED, __HIP_MEMORY_SCOPE_AGENT);
    int k = blockIdx.x * 256 + threadIdx.x; // <<<2,256>>>
    const float4* e4 = reinterpret_cast<const float4*>(emb + k * D);
    unsigned short h[D];
    float acc = 0.f;
#pragma unroll
    for (int i = 0; i < 16; ++i) {
        float4 v = e4[i];
        acc += v.x * v.x + v.y * v.y + v.z * v.z + v.w * v.w;
        h[4 * i + 0] = f2bf(v.x); h[4 * i + 1] = f2bf(v.y);
        h[4 * i + 2] = f2bf(v.z); h[4 * i + 3] = f2bf(v.w);
    }
    npm[k] = -0.5f * (1.0f + acc);
    uint4* dst = reinterpret_cast<uint4*>(ebf + k * D);
#pragma unroll
    for (int i = 0; i < 8; ++i) {
        uint4 p;
        p.x = (unsigned)h[8 * i + 0] | ((unsigned)h[8 * i + 1] << 16);
        p.y = (unsigned)h[8 * i + 2] | ((unsigned)h[8 * i + 3] << 16);
        p.z = (unsigned)h[8 * i + 4] | ((unsigned)h[8 * i + 5] << 16);
        p.w = (unsigned)h[8 * i + 6] | ((unsigned)h[8 * i + 7] << 16);
        dst[i] = p;
    }
}

__global__ __launch_bounds__(256, 3) void vq_mfma(const float* __restrict__ in,
                                                  const unsigned short* __restrict__ ebf,
                                                  const float* __restrict__ npm,
                                                  const float* __restrict__ emb,
                                                  float* __restrict__ out,
                                                  float* __restrict__ partials,
                                                  unsigned* __restrict__ cnt) {
    __shared__ __align__(16) char ldsX[16384]; // 128 rows x 128B bf16, swizzled
    __shared__ __align__(16) unsigned keysS[4][128];
    __shared__ float red4[4];
    __shared__ float fin[256];
    __shared__ int doneF;

    const int tid = threadIdx.x;
    const int lane = tid & 63;
    const int w = tid >> 6;
    const int col = lane & 15;
    const int dg = lane >> 4;
    const int bid = blockIdx.x;
    const int n = bid >> 5;
    const int hw0 = (bid & 31) << 7;

    // ---- stage X tile: NCHW -> [row][d] bf16, swizzled ----
    {
        const int row = tid & 127;
        const int half = tid >> 7;
        const float* xb = in + n * CHW + hw0 + row;
#pragma unroll
        for (int cg = 0; cg < 4; ++cg) {
            const int cgi = half * 4 + cg;
            unsigned short h[8];
#pragma unroll
            for (int j = 0; j < 8; ++j) h[j] = f2bf(xb[(cgi * 8 + j) * HW]);
            uint4 p;
            p.x = (unsigned)h[0] | ((unsigned)h[1] << 16);
            p.y = (unsigned)h[2] | ((unsigned)h[3] << 16);
            p.z = (unsigned)h[4] | ((unsigned)h[5] << 16);
            p.w = (unsigned)h[6] | ((unsigned)h[7] << 16);
            *reinterpret_cast<uint4*>(ldsX + row * 128 + ((cgi ^ SWZ(row)) * 16)) = p;
        }
    }

    unsigned best[8][4];
#pragma unroll
    for (int rt = 0; rt < 8; ++rt)
#pragma unroll
        for (int i = 0; i < 4; ++i) best[rt][i] = 0xFFFFFFFFu;

    // ---- main loop: 2 code-groups of 64; ef regs (32 VGPR) reused per group ----
    const short8* e8 = reinterpret_cast<const short8*>(ebf);
#pragma unroll 1
    for (int g = 0; g < 2; ++g) {
        const int kb = w * 128 + g * 64 + col;
        short8 ef[4][2];
        float npv[4];
#pragma unroll
        for (int ct = 0; ct < 4; ++ct) {
            const int k = kb + ct * 16;
            ef[ct][0] = e8[k * 8 + dg];
            ef[ct][1] = e8[k * 8 + 4 + dg];
            npv[ct] = npm[k];
        }
        if (g == 0) __syncthreads(); // g0 E-loads issued before the X barrier

#pragma unroll
        for (int rt = 0; rt < 8; ++rt) {
            const int row = rt * 16 + col;
            short8 a0 = *reinterpret_cast<const short8*>(
                ldsX + row * 128 + ((dg ^ SWZ(row)) * 16));
            short8 a1 = *reinterpret_cast<const short8*>(
                ldsX + row * 128 + (((4 + dg) ^ SWZ(row)) * 16));
#pragma unroll
            for (int ct = 0; ct < 4; ++ct) {
                // acc = x.e - 0.5*(1+||e||^2) = -crit/2 < 0; among negatives the
                // smallest uint is the least-negative float = smallest crit.
                f32x4 acc = {npv[ct], npv[ct], npv[ct], npv[ct]};
                acc = __builtin_amdgcn_mfma_f32_16x16x32_bf16(a0, ef[ct][0], acc, 0, 0, 0);
                acc = __builtin_amdgcn_mfma_f32_16x16x32_bf16(a1, ef[ct][1], acc, 0, 0, 0);
                const unsigned kc = (unsigned)(kb + ct * 16);
#pragma unroll
                for (int i = 0; i < 4; ++i) {
                    unsigned key = (__float_as_uint(acc[i]) & 0xFFFFFE00u) | kc;
                    best[rt][i] = umin32(best[rt][i], key);
                }
            }
        }
    }

    // ---- per-row argmin across the 16 code-columns; write per-wave keys ----
#pragma unroll
    for (int rt = 0; rt < 8; ++rt)
#pragma unroll
        for (int i = 0; i < 4; ++i) {
            unsigned k = best[rt][i];
#pragma unroll
            for (int s = 1; s < 16; s <<= 1)
                k = umin32(k, (unsigned)__shfl_xor((int)k, s, 64));
            if (col == 0) keysS[w][rt * 16 + dg * 4 + i] = k;
        }
    __syncthreads();

    // ---- epilogue: thread owns 4 rows x 8 channels; merge waves in-thread ----
    const int rg = tid & 31;  // row group (4 rows)
    const int cs = tid >> 5;  // channel set (8 channels)
    uint4 q0 = *reinterpret_cast<const uint4*>(&keysS[0][rg * 4]);
    uint4 q1 = *reinterpret_cast<const uint4*>(&keysS[1][rg * 4]);
    uint4 q2 = *reinterpret_cast<const uint4*>(&keysS[2][rg * 4]);
    uint4 q3 = *reinterpret_cast<const uint4*>(&keysS[3][rg * 4]);
    int kk[4];
    kk[0] = (int)(umin32(umin32(q0.x, q1.x), umin32(q2.x, q3.x)) & 511u);
    kk[1] = (int)(umin32(umin32(q0.y, q1.y), umin32(q2.y, q3.y)) & 511u);
    kk[2] = (int)(umin32(umin32(q0.z, q1.z), umin32(q2.z, q3.z)) & 511u);
    kk[3] = (int)(umin32(umin32(q0.w, q1.w), umin32(q2.w, q3.w)) & 511u);
    float ej[4][8];
#pragma unroll
    for (int j = 0; j < 4; ++j) {
        const float4* ep = reinterpret_cast<const float4*>(emb + kk[j] * D + cs * 8);
        *reinterpret_cast<float4*>(&ej[j][0]) = ep[0];
        *reinterpret_cast<float4*>(&ej[j][4]) = ep[1];
    }
    float lsum = 0.f;
#pragma unroll
    for (int j = 0; j < 4; ++j) {
        const int r = rg * 4 + j;
        short8 x8 = *reinterpret_cast<const short8*>(
            ldsX + r * 128 + ((cs ^ SWZ(r)) * 16));
#pragma unroll
        for (int t = 0; t < 8; ++t) {
            float d = ej[j][t] - bf2f((unsigned short)x8[t]);
            lsum = fmaf(d, d, lsum);
        }
    }
    float* obase = out + n * CHW + hw0 + rg * 4;
#pragma unroll
    for (int t = 0; t < 8; ++t) {
        float4 st;
        st.x = ej[0][t]; st.y = ej[1][t]; st.z = ej[2][t]; st.w = ej[3][t];
        *reinterpret_cast<float4*>(obase + (cs * 8 + t) * HW) = st;
    }

    // ---- loss partial + deterministic last-block finalize ----
#pragma unroll
    for (int s = 1; s < 64; s <<= 1) lsum += __shfl_xor(lsum, s, 64);
    if (lane == 0) red4[w] = lsum;
    __syncthreads();
    if (tid == 0) {
        float p = red4[0] + red4[1] + red4[2] + red4[3];
        __hip_atomic_store(&partials[bid], p, __ATOMIC_RELAXED, __HIP_MEMORY_SCOPE_AGENT);
        __threadfence(); // release: partials visible before ticket
        unsigned t = atomicAdd(cnt, 1u);
        doneF = (t == NB_MAIN - 1) ? 1 : 0;
    }
    __syncthreads();
    if (doneF) {
        __threadfence(); // acquire
        float a = 0.f;
#pragma unroll
        for (int i = 0; i < 4; ++i)
            a += __hip_atomic_load(&partials[tid + 256 * i], __ATOMIC_RELAXED,
                                   __HIP_MEMORY_SCOPE_AGENT);
        fin[tid] = a;
        __syncthreads();
        for (int t2 = 128; t2 > 0; t2 >>= 1) {
            if (tid < t2) fin[tid] += fin[tid + t2];
            __syncthreads();
        }
        if (tid == 0) out[OUT_ELEMS] = 1.25f * fin[0] * (1.0f / (float)OUT_ELEMS);
    }
}

extern "C" void kernel_launch(void* const* d_in, const int* in_sizes, int n_in,
                              void* d_out, int out_size, void* d_ws, size_t ws_size,
                              hipStream_t stream) {
    const float* in = (const float*)d_in[0];
    const float* emb = (const float*)d_in[1];
    float* out = (float*)d_out;
    unsigned short* ebf = (unsigned short*)d_ws;
    float* npm = (float*)((char*)d_ws + 65536);
    float* partials = (float*)((char*)d_ws + 67584);
    unsigned* cnt = (unsigned*)((char*)d_ws + 71680);

    vq_prep<<<2, 256, 0, stream>>>(emb, ebf, npm, cnt);
    vq_mfma<<<NB_MAIN, 256, 0, stream>>>(in, ebf, npm, emb, out, partials, cnt);
}

// Round 6
// 66.753 us; speedup vs baseline: 1.6272x; 1.0142x over previous
//
#include <hip/hip_runtime.h>

// VectorQuantizer, round 6: R5 + bijective XCD-aware block swizzle (only change).
// Consecutive logical tiles (adjacent hw of the same NCHW planes) now map to the
// same XCD/L2, enabling write-combining + DRAM row locality for the 512B chunks.
// inputs: in [32,64,64,64] fp32 NCHW, emb [512,64] fp32.
// out[0:8388608] = quantized NCHW, out[8388608] = loss.
// ws: [0,65536)B emb bf16; [65536,+2048) npm = -0.5*(1+||e||^2); [67584,+4096) partials;
//     [71680] ticket counter.

#define D 64
#define K_EMB 512
#define HW 4096
#define CHW (D * HW)
#define OUT_ELEMS 8388608
#define NB_MAIN 1024 // 131072 rows / 128 rows per block
#define SWZ(r) ((((r) ^ ((r) >> 2))) & 7)

typedef __attribute__((ext_vector_type(8))) short short8;
typedef __attribute__((ext_vector_type(4))) float f32x4;

__device__ __forceinline__ unsigned short f2bf(float f) {
    unsigned u = __float_as_uint(f);
    u += 0x7FFFu + ((u >> 16) & 1u); // RNE
    return (unsigned short)(u >> 16);
}
__device__ __forceinline__ float bf2f(unsigned short h) {
    return __uint_as_float(((unsigned)h) << 16);
}
__device__ __forceinline__ unsigned umin32(unsigned a, unsigned b) { return a <= b ? a : b; }

// Prep: codebook fp32 -> bf16 rows, npm = -0.5*(1+||e||^2), zero the ticket.
__global__ void vq_prep(const float* __restrict__ emb, unsigned short* __restrict__ ebf,
                        float* __restrict__ npm, unsigned* __restrict__ cnt) {
    if (blockIdx.x == 0 && threadIdx.x == 0)
        __hip_atomic_store(cnt, 0u, __ATOMIC_RELAXED, __HIP_MEMORY_SCOPE_AGENT);
    int k = blockIdx.x * 256 + threadIdx.x; // <<<2,256>>>
    const float4* e4 = reinterpret_cast<const float4*>(emb + k * D);
    unsigned short h[D];
    float acc = 0.f;
#pragma unroll
    for (int i = 0; i < 16; ++i) {
        float4 v = e4[i];
        acc += v.x * v.x + v.y * v.y + v.z * v.z + v.w * v.w;
        h[4 * i + 0] = f2bf(v.x); h[4 * i + 1] = f2bf(v.y);
        h[4 * i + 2] = f2bf(v.z); h[4 * i + 3] = f2bf(v.w);
    }
    npm[k] = -0.5f * (1.0f + acc);
    uint4* dst = reinterpret_cast<uint4*>(ebf + k * D);
#pragma unroll
    for (int i = 0; i < 8; ++i) {
        uint4 p;
        p.x = (unsigned)h[8 * i + 0] | ((unsigned)h[8 * i + 1] << 16);
        p.y = (unsigned)h[8 * i + 2] | ((unsigned)h[8 * i + 3] << 16);
        p.z = (unsigned)h[8 * i + 4] | ((unsigned)h[8 * i + 5] << 16);
        p.w = (unsigned)h[8 * i + 6] | ((unsigned)h[8 * i + 7] << 16);
        dst[i] = p;
    }
}

__global__ __launch_bounds__(256, 3) void vq_mfma(const float* __restrict__ in,
                                                  const unsigned short* __restrict__ ebf,
                                                  const float* __restrict__ npm,
                                                  const float* __restrict__ emb,
                                                  float* __restrict__ out,
                                                  float* __restrict__ partials,
                                                  unsigned* __restrict__ cnt) {
    __shared__ __align__(16) char ldsX[16384]; // 128 rows x 128B bf16, swizzled
    __shared__ __align__(16) unsigned keysS[4][128];
    __shared__ float red4[4];
    __shared__ float fin[256];
    __shared__ int doneF;

    const int tid = threadIdx.x;
    const int lane = tid & 63;
    const int w = tid >> 6;
    const int col = lane & 15;
    const int dg = lane >> 4;
    // Bijective XCD swizzle: physical blocks round-robin over 8 XCDs, so give
    // each XCD a CONTIGUOUS run of 128 logical tiles (= 4 full images).
    const int bid = ((blockIdx.x & 7) << 7) | (blockIdx.x >> 3);
    const int n = bid >> 5;
    const int hw0 = (bid & 31) << 7;

    // ---- stage X tile: NCHW -> [row][d] bf16, swizzled ----
    {
        const int row = tid & 127;
        const int half = tid >> 7;
        const float* xb = in + n * CHW + hw0 + row;
#pragma unroll
        for (int cg = 0; cg < 4; ++cg) {
            const int cgi = half * 4 + cg;
            unsigned short h[8];
#pragma unroll
            for (int j = 0; j < 8; ++j) h[j] = f2bf(xb[(cgi * 8 + j) * HW]);
            uint4 p;
            p.x = (unsigned)h[0] | ((unsigned)h[1] << 16);
            p.y = (unsigned)h[2] | ((unsigned)h[3] << 16);
            p.z = (unsigned)h[4] | ((unsigned)h[5] << 16);
            p.w = (unsigned)h[6] | ((unsigned)h[7] << 16);
            *reinterpret_cast<uint4*>(ldsX + row * 128 + ((cgi ^ SWZ(row)) * 16)) = p;
        }
    }

    unsigned best[8][4];
#pragma unroll
    for (int rt = 0; rt < 8; ++rt)
#pragma unroll
        for (int i = 0; i < 4; ++i) best[rt][i] = 0xFFFFFFFFu;

    // ---- main loop: 2 code-groups of 64; ef regs (32 VGPR) reused per group ----
    const short8* e8 = reinterpret_cast<const short8*>(ebf);
#pragma unroll 1
    for (int g = 0; g < 2; ++g) {
        const int kb = w * 128 + g * 64 + col;
        short8 ef[4][2];
        float npv[4];
#pragma unroll
        for (int ct = 0; ct < 4; ++ct) {
            const int k = kb + ct * 16;
            ef[ct][0] = e8[k * 8 + dg];
            ef[ct][1] = e8[k * 8 + 4 + dg];
            npv[ct] = npm[k];
        }
        if (g == 0) __syncthreads(); // g0 E-loads issued before the X barrier

#pragma unroll
        for (int rt = 0; rt < 8; ++rt) {
            const int row = rt * 16 + col;
            short8 a0 = *reinterpret_cast<const short8*>(
                ldsX + row * 128 + ((dg ^ SWZ(row)) * 16));
            short8 a1 = *reinterpret_cast<const short8*>(
                ldsX + row * 128 + (((4 + dg) ^ SWZ(row)) * 16));
#pragma unroll
            for (int ct = 0; ct < 4; ++ct) {
                // acc = x.e - 0.5*(1+||e||^2) = -crit/2 < 0; among negatives the
                // smallest uint is the least-negative float = smallest crit.
                f32x4 acc = {npv[ct], npv[ct], npv[ct], npv[ct]};
                acc = __builtin_amdgcn_mfma_f32_16x16x32_bf16(a0, ef[ct][0], acc, 0, 0, 0);
                acc = __builtin_amdgcn_mfma_f32_16x16x32_bf16(a1, ef[ct][1], acc, 0, 0, 0);
                const unsigned kc = (unsigned)(kb + ct * 16);
#pragma unroll
                for (int i = 0; i < 4; ++i) {
                    unsigned key = (__float_as_uint(acc[i]) & 0xFFFFFE00u) | kc;
                    best[rt][i] = umin32(best[rt][i], key);
                }
            }
        }
    }

    // ---- per-row argmin across the 16 code-columns; write per-wave keys ----
#pragma unroll
    for (int rt = 0; rt < 8; ++rt)
#pragma unroll
        for (int i = 0; i < 4; ++i) {
            unsigned k = best[rt][i];
#pragma unroll
            for (int s = 1; s < 16; s <<= 1)
                k = umin32(k, (unsigned)__shfl_xor((int)k, s, 64));
            if (col == 0) keysS[w][rt * 16 + dg * 4 + i] = k;
        }
    __syncthreads();

    // ---- epilogue: thread owns 4 rows x 8 channels; merge waves in-thread ----
    const int rg = tid & 31;  // row group (4 rows)
    const int cs = tid >> 5;  // channel set (8 channels)
    uint4 q0 = *reinterpret_cast<const uint4*>(&keysS[0][rg * 4]);
    uint4 q1 = *reinterpret_cast<const uint4*>(&keysS[1][rg * 4]);
    uint4 q2 = *reinterpret_cast<const uint4*>(&keysS[2][rg * 4]);
    uint4 q3 = *reinterpret_cast<const uint4*>(&keysS[3][rg * 4]);
    int kk[4];
    kk[0] = (int)(umin32(umin32(q0.x, q1.x), umin32(q2.x, q3.x)) & 511u);
    kk[1] = (int)(umin32(umin32(q0.y, q1.y), umin32(q2.y, q3.y)) & 511u);
    kk[2] = (int)(umin32(umin32(q0.z, q1.z), umin32(q2.z, q3.z)) & 511u);
    kk[3] = (int)(umin32(umin32(q0.w, q1.w), umin32(q2.w, q3.w)) & 511u);
    float ej[4][8];
#pragma unroll
    for (int j = 0; j < 4; ++j) {
        const float4* ep = reinterpret_cast<const float4*>(emb + kk[j] * D + cs * 8);
        *reinterpret_cast<float4*>(&ej[j][0]) = ep[0];
        *reinterpret_cast<float4*>(&ej[j][4]) = ep[1];
    }
    float lsum = 0.f;
#pragma unroll
    for (int j = 0; j < 4; ++j) {
        const int r = rg * 4 + j;
        short8 x8 = *reinterpret_cast<const short8*>(
            ldsX + r * 128 + ((cs ^ SWZ(r)) * 16));
#pragma unroll
        for (int t = 0; t < 8; ++t) {
            float d = ej[j][t] - bf2f((unsigned short)x8[t]);
            lsum = fmaf(d, d, lsum);
        }
    }
    float* obase = out + n * CHW + hw0 + rg * 4;
#pragma unroll
    for (int t = 0; t < 8; ++t) {
        float4 st;
        st.x = ej[0][t]; st.y = ej[1][t]; st.z = ej[2][t]; st.w = ej[3][t];
        *reinterpret_cast<float4*>(obase + (cs * 8 + t) * HW) = st;
    }

    // ---- loss partial + deterministic last-block finalize ----
#pragma unroll
    for (int s = 1; s < 64; s <<= 1) lsum += __shfl_xor(lsum, s, 64);
    if (lane == 0) red4[w] = lsum;
    __syncthreads();
    if (tid == 0) {
        float p = red4[0] + red4[1] + red4[2] + red4[3];
        __hip_atomic_store(&partials[bid], p, __ATOMIC_RELAXED, __HIP_MEMORY_SCOPE_AGENT);
        __threadfence(); // release: partials visible before ticket
        unsigned t = atomicAdd(cnt, 1u);
        doneF = (t == NB_MAIN - 1) ? 1 : 0;
    }
    __syncthreads();
    if (doneF) {
        __threadfence(); // acquire
        float a = 0.f;
#pragma unroll
        for (int i = 0; i < 4; ++i)
            a += __hip_atomic_load(&partials[tid + 256 * i], __ATOMIC_RELAXED,
                                   __HIP_MEMORY_SCOPE_AGENT);
        fin[tid] = a;
        __syncthreads();
        for (int t2 = 128; t2 > 0; t2 >>= 1) {
            if (tid < t2) fin[tid] += fin[tid + t2];
            __syncthreads();
        }
        if (tid == 0) out[OUT_ELEMS] = 1.25f * fin[0] * (1.0f / (float)OUT_ELEMS);
    }
}

extern "C" void kernel_launch(void* const* d_in, const int* in_sizes, int n_in,
                              void* d_out, int out_size, void* d_ws, size_t ws_size,
                              hipStream_t stream) {
    const float* in = (const float*)d_in[0];
    const float* emb = (const float*)d_in[1];
    float* out = (float*)d_out;
    unsigned short* ebf = (unsigned short*)d_ws;
    float* npm = (float*)((char*)d_ws + 65536);
    float* partials = (float*)((char*)d_ws + 67584);
    unsigned* cnt = (unsigned*)((char*)d_ws + 71680);

    vq_prep<<<2, 256, 0, stream>>>(emb, ebf, npm, cnt);
    vq_mfma<<<NB_MAIN, 256, 0, stream>>>(in, ebf, npm, emb, out, partials, cnt);
}

// Round 8
// 32.890 us; speedup vs baseline: 3.3024x; 2.0295x over previous
//
#include <hip/hip_runtime.h>

// VectorQuantizer, round 8 (= R7 with compile fix): no fence/ticket finalize,
// non-temporal output stores via ext_vector f32x4.
// inputs: in [32,64,64,64] fp32 NCHW, emb [512,64] fp32.
// out[0:8388608] = quantized NCHW, out[8388608] = loss.
// ws: [0,65536)B emb bf16; [65536,+2048) npm = -0.5*(1+||e||^2); [67584,+4096) partials.

#define D 64
#define K_EMB 512
#define HW 4096
#define CHW (D * HW)
#define OUT_ELEMS 8388608
#define NB_MAIN 1024 // 131072 rows / 128 rows per block
#define SWZ(r) ((((r) ^ ((r) >> 2))) & 7)

typedef __attribute__((ext_vector_type(8))) short short8;
typedef __attribute__((ext_vector_type(4))) float f32x4;

__device__ __forceinline__ unsigned short f2bf(float f) {
    unsigned u = __float_as_uint(f);
    u += 0x7FFFu + ((u >> 16) & 1u); // RNE
    return (unsigned short)(u >> 16);
}
__device__ __forceinline__ float bf2f(unsigned short h) {
    return __uint_as_float(((unsigned)h) << 16);
}
__device__ __forceinline__ unsigned umin32(unsigned a, unsigned b) { return a <= b ? a : b; }

// Prep: codebook fp32 -> bf16 rows + npm = -0.5*(1+||e||^2).
__global__ void vq_prep(const float* __restrict__ emb, unsigned short* __restrict__ ebf,
                        float* __restrict__ npm) {
    int k = blockIdx.x * 256 + threadIdx.x; // <<<2,256>>>
    const float4* e4 = reinterpret_cast<const float4*>(emb + k * D);
    unsigned short h[D];
    float acc = 0.f;
#pragma unroll
    for (int i = 0; i < 16; ++i) {
        float4 v = e4[i];
        acc += v.x * v.x + v.y * v.y + v.z * v.z + v.w * v.w;
        h[4 * i + 0] = f2bf(v.x); h[4 * i + 1] = f2bf(v.y);
        h[4 * i + 2] = f2bf(v.z); h[4 * i + 3] = f2bf(v.w);
    }
    npm[k] = -0.5f * (1.0f + acc);
    uint4* dst = reinterpret_cast<uint4*>(ebf + k * D);
#pragma unroll
    for (int i = 0; i < 8; ++i) {
        uint4 p;
        p.x = (unsigned)h[8 * i + 0] | ((unsigned)h[8 * i + 1] << 16);
        p.y = (unsigned)h[8 * i + 2] | ((unsigned)h[8 * i + 3] << 16);
        p.z = (unsigned)h[8 * i + 4] | ((unsigned)h[8 * i + 5] << 16);
        p.w = (unsigned)h[8 * i + 6] | ((unsigned)h[8 * i + 7] << 16);
        dst[i] = p;
    }
}

__global__ __launch_bounds__(256, 3) void vq_mfma(const float* __restrict__ in,
                                                  const unsigned short* __restrict__ ebf,
                                                  const float* __restrict__ npm,
                                                  const float* __restrict__ emb,
                                                  float* __restrict__ out,
                                                  float* __restrict__ partials) {
    __shared__ __align__(16) char ldsX[16384]; // 128 rows x 128B bf16, swizzled
    __shared__ __align__(16) unsigned keysS[4][128];
    __shared__ float red4[4];

    const int tid = threadIdx.x;
    const int lane = tid & 63;
    const int w = tid >> 6;
    const int col = lane & 15;
    const int dg = lane >> 4;
    // Bijective XCD swizzle (kept from R6; neutral).
    const int bid = ((blockIdx.x & 7) << 7) | (blockIdx.x >> 3);
    const int n = bid >> 5;
    const int hw0 = (bid & 31) << 7;

    // ---- stage X tile: NCHW -> [row][d] bf16, swizzled ----
    {
        const int row = tid & 127;
        const int half = tid >> 7;
        const float* xb = in + n * CHW + hw0 + row;
#pragma unroll
        for (int cg = 0; cg < 4; ++cg) {
            const int cgi = half * 4 + cg;
            unsigned short h[8];
#pragma unroll
            for (int j = 0; j < 8; ++j) h[j] = f2bf(xb[(cgi * 8 + j) * HW]);
            uint4 p;
            p.x = (unsigned)h[0] | ((unsigned)h[1] << 16);
            p.y = (unsigned)h[2] | ((unsigned)h[3] << 16);
            p.z = (unsigned)h[4] | ((unsigned)h[5] << 16);
            p.w = (unsigned)h[6] | ((unsigned)h[7] << 16);
            *reinterpret_cast<uint4*>(ldsX + row * 128 + ((cgi ^ SWZ(row)) * 16)) = p;
        }
    }

    unsigned best[8][4];
#pragma unroll
    for (int rt = 0; rt < 8; ++rt)
#pragma unroll
        for (int i = 0; i < 4; ++i) best[rt][i] = 0xFFFFFFFFu;

    // ---- main loop: 2 code-groups of 64; ef regs (32 VGPR) reused per group ----
    const short8* e8 = reinterpret_cast<const short8*>(ebf);
#pragma unroll 1
    for (int g = 0; g < 2; ++g) {
        const int kb = w * 128 + g * 64 + col;
        short8 ef[4][2];
        float npv[4];
#pragma unroll
        for (int ct = 0; ct < 4; ++ct) {
            const int k = kb + ct * 16;
            ef[ct][0] = e8[k * 8 + dg];
            ef[ct][1] = e8[k * 8 + 4 + dg];
            npv[ct] = npm[k];
        }
        if (g == 0) __syncthreads(); // g0 E-loads issued before the X barrier

#pragma unroll
        for (int rt = 0; rt < 8; ++rt) {
            const int row = rt * 16 + col;
            short8 a0 = *reinterpret_cast<const short8*>(
                ldsX + row * 128 + ((dg ^ SWZ(row)) * 16));
            short8 a1 = *reinterpret_cast<const short8*>(
                ldsX + row * 128 + (((4 + dg) ^ SWZ(row)) * 16));
#pragma unroll
            for (int ct = 0; ct < 4; ++ct) {
                // acc = x.e - 0.5*(1+||e||^2) = -crit/2 < 0; among negatives the
                // smallest uint is the least-negative float = smallest crit.
                f32x4 acc = {npv[ct], npv[ct], npv[ct], npv[ct]};
                acc = __builtin_amdgcn_mfma_f32_16x16x32_bf16(a0, ef[ct][0], acc, 0, 0, 0);
                acc = __builtin_amdgcn_mfma_f32_16x16x32_bf16(a1, ef[ct][1], acc, 0, 0, 0);
                const unsigned kc = (unsigned)(kb + ct * 16);
#pragma unroll
                for (int i = 0; i < 4; ++i) {
                    unsigned key = (__float_as_uint(acc[i]) & 0xFFFFFE00u) | kc;
                    best[rt][i] = umin32(best[rt][i], key);
                }
            }
        }
    }

    // ---- per-row argmin across the 16 code-columns; write per-wave keys ----
#pragma unroll
    for (int rt = 0; rt < 8; ++rt)
#pragma unroll
        for (int i = 0; i < 4; ++i) {
            unsigned k = best[rt][i];
#pragma unroll
            for (int s = 1; s < 16; s <<= 1)
                k = umin32(k, (unsigned)__shfl_xor((int)k, s, 64));
            if (col == 0) keysS[w][rt * 16 + dg * 4 + i] = k;
        }
    __syncthreads();

    // ---- epilogue: thread owns 4 rows x 8 channels; merge waves in-thread ----
    const int rg = tid & 31;  // row group (4 rows)
    const int cs = tid >> 5;  // channel set (8 channels)
    uint4 q0 = *reinterpret_cast<const uint4*>(&keysS[0][rg * 4]);
    uint4 q1 = *reinterpret_cast<const uint4*>(&keysS[1][rg * 4]);
    uint4 q2 = *reinterpret_cast<const uint4*>(&keysS[2][rg * 4]);
    uint4 q3 = *reinterpret_cast<const uint4*>(&keysS[3][rg * 4]);
    int kk[4];
    kk[0] = (int)(umin32(umin32(q0.x, q1.x), umin32(q2.x, q3.x)) & 511u);
    kk[1] = (int)(umin32(umin32(q0.y, q1.y), umin32(q2.y, q3.y)) & 511u);
    kk[2] = (int)(umin32(umin32(q0.z, q1.z), umin32(q2.z, q3.z)) & 511u);
    kk[3] = (int)(umin32(umin32(q0.w, q1.w), umin32(q2.w, q3.w)) & 511u);
    float ej[4][8];
#pragma unroll
    for (int j = 0; j < 4; ++j) {
        const f32x4* ep = reinterpret_cast<const f32x4*>(emb + kk[j] * D + cs * 8);
        *reinterpret_cast<f32x4*>(&ej[j][0]) = ep[0];
        *reinterpret_cast<f32x4*>(&ej[j][4]) = ep[1];
    }
    float lsum = 0.f;
#pragma unroll
    for (int j = 0; j < 4; ++j) {
        const int r = rg * 4 + j;
        short8 x8 = *reinterpret_cast<const short8*>(
            ldsX + r * 128 + ((cs ^ SWZ(r)) * 16));
#pragma unroll
        for (int t = 0; t < 8; ++t) {
            float d = ej[j][t] - bf2f((unsigned short)x8[t]);
            lsum = fmaf(d, d, lsum);
        }
    }
    float* obase = out + n * CHW + hw0 + rg * 4;
#pragma unroll
    for (int t = 0; t < 8; ++t) {
        f32x4 st = {ej[0][t], ej[1][t], ej[2][t], ej[3][t]};
        __builtin_nontemporal_store(st, reinterpret_cast<f32x4*>(obase + (cs * 8 + t) * HW));
    }

    // ---- loss partial (plain store; separate finalize kernel) ----
#pragma unroll
    for (int s = 1; s < 64; s <<= 1) lsum += __shfl_xor(lsum, s, 64);
    if (lane == 0) red4[w] = lsum;
    __syncthreads();
    if (tid == 0) partials[bid] = red4[0] + red4[1] + red4[2] + red4[3];
}

__global__ void vq_finalize(const float* __restrict__ partials, float* __restrict__ loss) {
    __shared__ float s[256];
    float a = 0.f;
    for (int i = threadIdx.x; i < NB_MAIN; i += 256) a += partials[i];
    s[threadIdx.x] = a;
    __syncthreads();
    for (int t = 128; t > 0; t >>= 1) {
        if ((int)threadIdx.x < t) s[threadIdx.x] += s[threadIdx.x + t];
        __syncthreads();
    }
    if (threadIdx.x == 0) loss[0] = 1.25f * s[0] * (1.0f / (float)OUT_ELEMS);
}

extern "C" void kernel_launch(void* const* d_in, const int* in_sizes, int n_in,
                              void* d_out, int out_size, void* d_ws, size_t ws_size,
                              hipStream_t stream) {
    const float* in = (const float*)d_in[0];
    const float* emb = (const float*)d_in[1];
    float* out = (float*)d_out;
    unsigned short* ebf = (unsigned short*)d_ws;
    float* npm = (float*)((char*)d_ws + 65536);
    float* partials = (float*)((char*)d_ws + 67584);

    vq_prep<<<2, 256, 0, stream>>>(emb, ebf, npm);
    vq_mfma<<<NB_MAIN, 256, 0, stream>>>(in, ebf, npm, emb, out, partials);
    vq_finalize<<<1, 256, 0, stream>>>(partials, out + OUT_ELEMS);
}